// Round 14
// baseline (460.229 us; speedup 1.0000x reference)
//
#include <hip/hip_runtime.h>
#include <hip/hip_bf16.h>

typedef short bf16x8 __attribute__((ext_vector_type(8)));
typedef float f32x4 __attribute__((ext_vector_type(4)));
typedef unsigned short ushort8v __attribute__((ext_vector_type(8)));

#define SBAR() asm volatile("s_barrier" ::: "memory")
#define SB0() __builtin_amdgcn_sched_barrier(0)
#define LGKM0() do { asm volatile("s_waitcnt lgkmcnt(0)" ::: "memory"); SB0(); } while (0)

__device__ __forceinline__ unsigned short f2bf(float f) {
  unsigned u = __builtin_bit_cast(unsigned, f);
  u += 0x7fffu + ((u >> 16) & 1u);   // round-to-nearest-even
  return (unsigned short)(u >> 16);
}

__device__ __forceinline__ void gload_lds16(const unsigned short* g, unsigned short* l) {
  __builtin_amdgcn_global_load_lds((const __attribute__((address_space(1))) void*)g,
                                   (__attribute__((address_space(3))) void*)l, 16, 0, 0);
}

// ---------------- fused prep: xb = bf16(x); wb = bf16(W + scale*B@A) ----------------
__global__ __launch_bounds__(256) void prep_kernel(const float* __restrict__ x,
                                                   const float* __restrict__ W,
                                                   const float* __restrict__ A,
                                                   const float* __restrict__ Bm,
                                                   unsigned short* __restrict__ xb,
                                                   unsigned short* __restrict__ wb,
                                                   float scale, int K, int R, int n8, int t8) {
  int i = blockIdx.x * 256 + threadIdx.x;
  if (i < n8) {
    const float4* p = (const float4*)x + (size_t)i * 2;
    float4 a = p[0], b = p[1];
    ushort8v v;
    v[0] = f2bf(a.x); v[1] = f2bf(a.y); v[2] = f2bf(a.z); v[3] = f2bf(a.w);
    v[4] = f2bf(b.x); v[5] = f2bf(b.y); v[6] = f2bf(b.z); v[7] = f2bf(b.w);
    *((ushort8v*)xb + i) = v;
    return;
  }
  int idx = i - n8;
  if (idx >= t8) return;
  int perRow = K >> 3;
  int n = idx / perRow;
  int d0 = (idx - n * perRow) << 3;
  const float4* wp = (const float4*)(W + (size_t)n * K + d0);
  float4 w0 = wp[0], w1 = wp[1];
  float acc[8] = {w0.x, w0.y, w0.z, w0.w, w1.x, w1.y, w1.z, w1.w};
#pragma unroll 4
  for (int r = 0; r < R; ++r) {
    float c = Bm[(size_t)n * R + r] * scale;
    const float4* ap = (const float4*)(A + (size_t)r * K + d0);
    float4 a0 = ap[0], a1 = ap[1];
    acc[0] += c * a0.x; acc[1] += c * a0.y; acc[2] += c * a0.z; acc[3] += c * a0.w;
    acc[4] += c * a1.x; acc[5] += c * a1.y; acc[6] += c * a1.z; acc[7] += c * a1.w;
  }
  ushort8v v;
#pragma unroll
  for (int j = 0; j < 8; ++j) v[j] = f2bf(acc[j]);
  *((ushort8v*)wb + idx) = v;
}

// ------- 256x256 bf16 GEMM: 4 waves x (128x128) -- LDS-traffic-minimized -------
// Additive-pipe model (validated r8-r13): K-step = MFMA(2483cyc) + LDSreads + bar.
// LDS reads scale with (waveM+waveN): 4 waves of 128x128 -> 128 b128/CU/K-step
// vs 8 waves of 128x64 -> 192. Same MFMA work, same staging volume.
// BK=64, 2 LDS buffers (2x64KB). acc[8][8] f32x4 = 256 VGPR (1 wave/SIMD, cap 512).
// A sites (8KB, 64 rows): s=qm*2+wr -> rows wr*128+qm*64..+63; B same with wc/qn.
// Phases: P1 (qm0,qn0: read aF8+bF0 8), P2 (qm0,qn1: read bF1 8),
//         P3 (qm1,qn0: refill aF 8), P4 (qm1,qn1: 0 reads). 32 MFMA each.
// Stage tile c+1: P1 A-s01, P2 B-s01, P3 B-s23, P4 A-s23 (4 gloads each).
// vmcnt ledger (certs always >=2 phases aged, reads after cert-barrier):
//   vmcnt(8)@P1 certifies B-s23(c) for P2; vmcnt(8)@P2 certifies A-s23(c) for P3;
//   vmcnt(4)@P4 certifies A-s01/B-s01(c+1) for next P1. Tail: 4/0/0.
// Swizzle: 16B-chunk q of row r holds global chunk q^(r&7) (measured 0 conflicts).
__global__ __launch_bounds__(256, 1) void gemm256x4_bt_bias(const unsigned short* __restrict__ Xb,
                                                            const unsigned short* __restrict__ Wb,
                                                            const float* __restrict__ bias,
                                                            float* __restrict__ C,
                                                            int M, int N, int K) {
  __shared__ __align__(16) char lds[131072];
  const int t = threadIdx.x;
  const int wave = t >> 6, lane = t & 63;
  const int fr = lane & 15, kc = lane >> 4;
  const int wr = wave >> 1, wc = wave & 1;

  const int NTn = N >> 8;
  const int nwg = gridDim.x;
  int bid = blockIdx.x;
  if ((nwg & 7) == 0) bid = (bid & 7) * (nwg >> 3) + (bid >> 3);  // XCD swizzle
  const int tm = bid / NTn, tn = bid % NTn;
  const int m0 = tm << 8, n0 = tn << 8;

  // staging sources (pre-swizzled global chunk)
  const int grow = t >> 3;                                // 0..31
  const int gch8 = ((t & 7) ^ (grow & 7)) << 3;
  const unsigned short* pa0 = Xb + (size_t)(m0 + grow) * K + gch8;
  const unsigned short* pb0 = Wb + (size_t)(n0 + grow) * K + gch8;
  const size_t K32 = (size_t)32 * K;
  const int sdst = t * 16;

  // read base pointers (conflict-free swizzle)
  const int swz = (fr & 7) << 4;
  const int cb0 = (kc << 4) ^ swz;
  const int cb1 = ((4 + kc) << 4) ^ swz;
  const char* rA0[2] = { (char*)lds + wr * 8192 + fr * 128 + cb0,
                         (char*)lds + 65536 + wr * 8192 + fr * 128 + cb0 };
  const char* rA1[2] = { (char*)lds + wr * 8192 + fr * 128 + cb1,
                         (char*)lds + 65536 + wr * 8192 + fr * 128 + cb1 };
  const char* rB0[2] = { (char*)lds + 32768 + wc * 8192 + fr * 128 + cb0,
                         (char*)lds + 98304 + wc * 8192 + fr * 128 + cb0 };
  const char* rB1[2] = { (char*)lds + 32768 + wc * 8192 + fr * 128 + cb1,
                         (char*)lds + 98304 + wc * 8192 + fr * 128 + cb1 };

  f32x4 acc[8][8];
#pragma unroll
  for (int m = 0; m < 8; ++m)
#pragma unroll
    for (int n = 0; n < 8; ++n) acc[m][n] = (f32x4){0.f, 0.f, 0.f, 0.f};

  bf16x8 aF[8], bF0[8], bF1[8];

#define GL(PSRC, DOFF) gload_lds16((PSRC), (unsigned short*)((char*)lds + (DOFF) + sdst))
#define STG_A01(BUF, COL) do { GL(pa0 + (COL), (BUF)*65536 + 0); \
    GL(pa0 + K32 + (COL), (BUF)*65536 + 4096); \
    GL(pa0 + 4*K32 + (COL), (BUF)*65536 + 8192); \
    GL(pa0 + 5*K32 + (COL), (BUF)*65536 + 12288); } while (0)
#define STG_A23(BUF, COL) do { GL(pa0 + 2*K32 + (COL), (BUF)*65536 + 16384); \
    GL(pa0 + 3*K32 + (COL), (BUF)*65536 + 20480); \
    GL(pa0 + 6*K32 + (COL), (BUF)*65536 + 24576); \
    GL(pa0 + 7*K32 + (COL), (BUF)*65536 + 28672); } while (0)
#define STG_B01(BUF, COL) do { GL(pb0 + (COL), (BUF)*65536 + 32768); \
    GL(pb0 + K32 + (COL), (BUF)*65536 + 36864); \
    GL(pb0 + 4*K32 + (COL), (BUF)*65536 + 40960); \
    GL(pb0 + 5*K32 + (COL), (BUF)*65536 + 45056); } while (0)
#define STG_B23(BUF, COL) do { GL(pb0 + 2*K32 + (COL), (BUF)*65536 + 49152); \
    GL(pb0 + 3*K32 + (COL), (BUF)*65536 + 53248); \
    GL(pb0 + 6*K32 + (COL), (BUF)*65536 + 57344); \
    GL(pb0 + 7*K32 + (COL), (BUF)*65536 + 61440); } while (0)

#define RD_A(BUF, QM) do { \
    const char* p0_ = rA0[BUF] + (QM)*16384; const char* p1_ = rA1[BUF] + (QM)*16384; \
    aF[0]=*(const bf16x8*)(p0_);      aF[1]=*(const bf16x8*)(p1_); \
    aF[2]=*(const bf16x8*)(p0_+2048); aF[3]=*(const bf16x8*)(p1_+2048); \
    aF[4]=*(const bf16x8*)(p0_+4096); aF[5]=*(const bf16x8*)(p1_+4096); \
    aF[6]=*(const bf16x8*)(p0_+6144); aF[7]=*(const bf16x8*)(p1_+6144); } while (0)
#define RD_B(BUF, QN, DST) do { \
    const char* p0_ = rB0[BUF] + (QN)*16384; const char* p1_ = rB1[BUF] + (QN)*16384; \
    DST[0]=*(const bf16x8*)(p0_);      DST[1]=*(const bf16x8*)(p1_); \
    DST[2]=*(const bf16x8*)(p0_+2048); DST[3]=*(const bf16x8*)(p1_+2048); \
    DST[4]=*(const bf16x8*)(p0_+4096); DST[5]=*(const bf16x8*)(p1_+4096); \
    DST[6]=*(const bf16x8*)(p0_+6144); DST[7]=*(const bf16x8*)(p1_+6144); } while (0)

#define MMQ(QM, QN, BF) do { \
    __builtin_amdgcn_s_setprio(1); \
    _Pragma("unroll") for (int ks = 0; ks < 2; ++ks) \
    _Pragma("unroll") for (int mi = 0; mi < 4; ++mi) \
    _Pragma("unroll") for (int ni = 0; ni < 4; ++ni) \
      acc[(QM)*4+mi][(QN)*4+ni] = __builtin_amdgcn_mfma_f32_16x16x32_bf16( \
          aF[mi*2+ks], BF[ni*2+ks], acc[(QM)*4+mi][(QN)*4+ni], 0, 0, 0); \
    __builtin_amdgcn_s_setprio(0); } while (0)

#define STEP(BUF, DOSTG, VM1, VM2, VM4) do { \
    /* P1: quadrant (0,0) */ \
    RD_A(BUF, 0); RD_B(BUF, 0, bF0); \
    if (DOSTG) { STG_A01((BUF)^1, col); } \
    asm volatile("s_waitcnt vmcnt(" VM1 ")" ::: "memory"); \
    SBAR(); LGKM0(); MMQ(0, 0, bF0); SBAR(); \
    /* P2: quadrant (0,1) */ \
    RD_B(BUF, 1, bF1); \
    if (DOSTG) { STG_B01((BUF)^1, col); } \
    asm volatile("s_waitcnt vmcnt(" VM2 ")" ::: "memory"); \
    SBAR(); LGKM0(); MMQ(0, 1, bF1); SBAR(); \
    /* P3: quadrant (1,0), refill aF */ \
    RD_A(BUF, 1); \
    if (DOSTG) { STG_B23((BUF)^1, col); } \
    SBAR(); LGKM0(); MMQ(1, 0, bF0); SBAR(); \
    /* P4: quadrant (1,1), no reads */ \
    if (DOSTG) { STG_A23((BUF)^1, col); } \
    asm volatile("s_waitcnt vmcnt(" VM4 ")" ::: "memory"); \
    SB0(); \
    SBAR(); MMQ(1, 1, bF1); SBAR(); \
    if (DOSTG) col += 64; \
  } while (0)

  // prologue: stage tile0 (A-s01, B-s01, B-s23, A-s23); certify A-s01+B-s01.
  size_t col = 0;
  STG_A01(0, 0); STG_B01(0, 0); STG_B23(0, 0); STG_A23(0, 0);
  asm volatile("s_waitcnt vmcnt(8)" ::: "memory");
  SBAR();
  col = 64;

  const int NS = K >> 6;   // even (K % 128 == 0 enforced by launcher)
  for (int s2 = 0; s2 < NS - 2; s2 += 2) {
    STEP(0, 1, "8", "8", "4");
    STEP(1, 1, "8", "8", "4");
  }
  STEP(0, 1, "8", "8", "4");   // step NS-2: stages tile NS-1
  STEP(1, 0, "4", "0", "0");   // step NS-1: drain tail

  // epilogue: D map col = lane&15, row = (lane>>4)*4 + reg
  const int crow = (lane >> 4) * 4;
  const int ccol = lane & 15;
#pragma unroll
  for (int ni = 0; ni < 8; ++ni) {
    int colI = n0 + wc * 128 + ni * 16 + ccol;
    float bv = bias[colI];
#pragma unroll
    for (int mi = 0; mi < 8; ++mi) {
      int row = m0 + wr * 128 + mi * 16 + crow;
      float* cp = C + (size_t)row * N + colI;
#pragma unroll
      for (int r = 0; r < 4; ++r) cp[(size_t)r * N] = acc[mi][ni][r] + bv;
    }
  }
#undef GL
#undef STG_A01
#undef STG_A23
#undef STG_B01
#undef STG_B23
#undef RD_A
#undef RD_B
#undef MMQ
#undef STEP
}

// ---------------- 128x128 m97-structure fallback GEMM ----------------
__global__ __launch_bounds__(256) void gemm_bt_bias(const unsigned short* __restrict__ Xb,
                                                    const unsigned short* __restrict__ Wb,
                                                    const float* __restrict__ bias,
                                                    float* __restrict__ C,
                                                    int M, int N, int K) {
  __shared__ unsigned short sA[128 * 32];
  __shared__ unsigned short sB[128 * 32];
  const int t = threadIdx.x;
  const int wave = t >> 6, lane = t & 63;
  const int NT = N >> 7;
  const int nwg = gridDim.x;
  int bid = blockIdx.x;
  if ((nwg & 7) == 0) bid = (bid & 7) * (nwg >> 3) + (bid >> 3);
  const int tm = bid / NT, tn = bid % NT;
  const int m0 = tm << 7, n0 = tn << 7;
  const int wr = wave >> 1, wc = wave & 1;

  f32x4 acc[4][4];
#pragma unroll
  for (int m = 0; m < 4; ++m)
#pragma unroll
    for (int n = 0; n < 4; ++n) acc[m][n] = (f32x4){0.f, 0.f, 0.f, 0.f};

  const unsigned short* gA0 = Xb + (size_t)(m0 + (t >> 2)) * K + (t & 3) * 8;
  const unsigned short* gA1 = Xb + (size_t)(m0 + 64 + (t >> 2)) * K + (t & 3) * 8;
  const unsigned short* gB0 = Wb + (size_t)(n0 + (t >> 2)) * K + (t & 3) * 8;
  const unsigned short* gB1 = Wb + (size_t)(n0 + 64 + (t >> 2)) * K + (t & 3) * 8;
  unsigned short* lA0 = sA + (size_t)(wave * 64) * 8;
  unsigned short* lA1 = sA + (size_t)(256 + wave * 64) * 8;
  unsigned short* lB0 = sB + (size_t)(wave * 64) * 8;
  unsigned short* lB1 = sB + (size_t)(256 + wave * 64) * 8;

  const int rrow = lane & 15;
  const int rk = (lane >> 4) * 8;

  for (int k0 = 0; k0 < K; k0 += 32) {
    gload_lds16(gA0 + k0, lA0);
    gload_lds16(gA1 + k0, lA1);
    gload_lds16(gB0 + k0, lB0);
    gload_lds16(gB1 + k0, lB1);
    __syncthreads();
    bf16x8 af[4], bfr[4];
#pragma unroll
    for (int m = 0; m < 4; ++m)
      af[m] = *(const bf16x8*)&sA[(size_t)(wr * 64 + m * 16 + rrow) * 32 + rk];
#pragma unroll
    for (int n = 0; n < 4; ++n)
      bfr[n] = *(const bf16x8*)&sB[(size_t)(wc * 64 + n * 16 + rrow) * 32 + rk];
#pragma unroll
    for (int m = 0; m < 4; ++m)
#pragma unroll
      for (int n = 0; n < 4; ++n)
        acc[m][n] = __builtin_amdgcn_mfma_f32_16x16x32_bf16(af[m], bfr[n], acc[m][n], 0, 0, 0);
    __syncthreads();
  }
  const int crow0 = (lane >> 4) * 4;
  const int ccol = lane & 15;
#pragma unroll
  for (int n = 0; n < 4; ++n) {
    int col = n0 + wc * 64 + n * 16 + ccol;
    float bv = bias[col];
#pragma unroll
    for (int m = 0; m < 4; ++m) {
      int row = m0 + wr * 64 + m * 16 + crow0;
      float* cp = C + (size_t)row * N + col;
#pragma unroll
      for (int r = 0; r < 4; ++r) cp[(size_t)r * N] = acc[m][n][r] + bv;
    }
  }
}

// ---------------- fp32 fallback ----------------
__global__ __launch_bounds__(64) void lora_h_kernel(const float* __restrict__ x,
                                                    const float* __restrict__ A,
                                                    float* __restrict__ h,
                                                    float scale, int K, int R) {
  int m = blockIdx.x, lane = threadIdx.x;
  float acc[16];
#pragma unroll
  for (int r = 0; r < 16; ++r) acc[r] = 0.f;
  for (int d = lane; d < K; d += 64) {
    float xv = x[(size_t)m * K + d];
    for (int r = 0; r < R; ++r) acc[r] += xv * A[(size_t)r * K + d];
  }
  for (int off = 32; off; off >>= 1)
    for (int r = 0; r < R; ++r) acc[r] += __shfl_down(acc[r], off);
  if (lane == 0)
    for (int r = 0; r < R; ++r) h[(size_t)m * R + r] = acc[r] * scale;
}

__global__ __launch_bounds__(256) void fgemm_fallback(const float* __restrict__ X,
                                                      const float* __restrict__ W,
                                                      const float* __restrict__ Bm,
                                                      const float* __restrict__ bias,
                                                      const float* __restrict__ h,
                                                      float* __restrict__ C,
                                                      int M, int N, int K, int R) {
  __shared__ float sX[64][20];
  __shared__ float sW[64][20];
  int nt = N >> 6;
  int bx = blockIdx.x % nt, by = blockIdx.x / nt;
  int m0 = by << 6, n0 = bx << 6;
  int t = threadIdx.x;
  int tx = t & 15, ty = t >> 4;
  float acc[4][4] = {};
  int lrr = t >> 2, lc = (t & 3) << 2;
  for (int k0 = 0; k0 < K; k0 += 16) {
    *(float4*)&sX[lrr][lc] = *(const float4*)&X[(size_t)(m0 + lrr) * K + k0 + lc];
    *(float4*)&sW[lrr][lc] = *(const float4*)&W[(size_t)(n0 + lrr) * K + k0 + lc];
    __syncthreads();
#pragma unroll
    for (int kk = 0; kk < 16; ++kk) {
      float a[4], b[4];
#pragma unroll
      for (int i = 0; i < 4; ++i) a[i] = sX[ty * 4 + i][kk];
#pragma unroll
      for (int j = 0; j < 4; ++j) b[j] = sW[tx * 4 + j][kk];
#pragma unroll
      for (int i = 0; i < 4; ++i)
#pragma unroll
        for (int j = 0; j < 4; ++j) acc[i][j] += a[i] * b[j];
    }
    __syncthreads();
  }
#pragma unroll
  for (int i = 0; i < 4; ++i) {
    int row = m0 + ty * 4 + i;
#pragma unroll
    for (int j = 0; j < 4; ++j) {
      int col = n0 + tx * 4 + j;
      float lo = 0.f;
      for (int r = 0; r < R; ++r) lo += h[(size_t)row * R + r] * Bm[(size_t)col * R + r];
      C[(size_t)row * N + col] = acc[i][j] + bias[col] + lo;
    }
  }
}

extern "C" void kernel_launch(void* const* d_in, const int* in_sizes, int n_in,
                              void* d_out, int out_size, void* d_ws, size_t ws_size,
                              hipStream_t stream) {
  const float* x    = (const float*)d_in[0];
  const float* W    = (const float*)d_in[1];
  const float* A    = (const float*)d_in[2];
  const float* Bm   = (const float*)d_in[3];
  const float* bias = (const float*)d_in[4];
  float* out = (float*)d_out;

  const int N = in_sizes[4];
  const int R = in_sizes[3] / N;
  const int K = in_sizes[2] / R;
  const int M = in_sizes[0] / K;
  const float scale = 16.0f / (float)R;

  const size_t xbytes = (size_t)M * K * 2;
  const size_t wbytes = (size_t)N * K * 2;
  const bool ws_ok = (ws_size >= xbytes + wbytes);
  const bool fast256 = ws_ok && (M % 256 == 0) && (N % 256 == 0) && (K % 128 == 0) && (K >= 256);
  const bool fast128 = ws_ok && (M % 128 == 0) && (N % 128 == 0) && (K % 32 == 0);

  if (fast256 || fast128) {
    unsigned short* xb = (unsigned short*)d_ws;
    unsigned short* wb = (unsigned short*)((char*)d_ws + xbytes);
    int n8 = M * K / 8;
    int t8 = N * K / 8;
    int total = n8 + t8;
    prep_kernel<<<dim3((total + 255) / 256), dim3(256), 0, stream>>>(x, W, A, Bm, xb, wb,
                                                                     scale, K, R, n8, t8);
    if (fast256) {
      int grid = (M / 256) * (N / 256);
      gemm256x4_bt_bias<<<dim3(grid), dim3(256), 0, stream>>>(xb, wb, bias, out, M, N, K);
    } else {
      int grid = (M / 128) * (N / 128);
      gemm_bt_bias<<<dim3(grid), dim3(256), 0, stream>>>(xb, wb, bias, out, M, N, K);
    }
  } else {
    float* h = (float*)d_ws;
    lora_h_kernel<<<dim3(M), dim3(64), 0, stream>>>(x, A, h, scale, K, R);
    int grid = (M / 64) * (N / 64);
    fgemm_fallback<<<dim3(grid), dim3(256), 0, stream>>>(x, W, Bm, bias, h, out, M, N, K, R);
  }
}

// Round 15
// 373.984 us; speedup vs baseline: 1.2306x; 1.2306x over previous
//
#include <hip/hip_runtime.h>
#include <hip/hip_bf16.h>

typedef short bf16x8 __attribute__((ext_vector_type(8)));
typedef float f32x4 __attribute__((ext_vector_type(4)));
typedef unsigned short ushort8v __attribute__((ext_vector_type(8)));

#define SBAR() asm volatile("s_barrier" ::: "memory")
#define SB0() __builtin_amdgcn_sched_barrier(0)
#define LGKM0() do { asm volatile("s_waitcnt lgkmcnt(0)" ::: "memory"); SB0(); } while (0)

__device__ __forceinline__ unsigned short f2bf(float f) {
  unsigned u = __builtin_bit_cast(unsigned, f);
  u += 0x7fffu + ((u >> 16) & 1u);   // round-to-nearest-even
  return (unsigned short)(u >> 16);
}

__device__ __forceinline__ void gload_lds16(const unsigned short* g, unsigned short* l) {
  __builtin_amdgcn_global_load_lds((const __attribute__((address_space(1))) void*)g,
                                   (__attribute__((address_space(3))) void*)l, 16, 0, 0);
}

// ---------------- fused prep: xb = bf16(x); wb = bf16(W + scale*B@A) ----------------
__global__ __launch_bounds__(256) void prep_kernel(const float* __restrict__ x,
                                                   const float* __restrict__ W,
                                                   const float* __restrict__ A,
                                                   const float* __restrict__ Bm,
                                                   unsigned short* __restrict__ xb,
                                                   unsigned short* __restrict__ wb,
                                                   float scale, int K, int R, int n8, int t8) {
  int i = blockIdx.x * 256 + threadIdx.x;
  if (i < n8) {
    const float4* p = (const float4*)x + (size_t)i * 2;
    float4 a = p[0], b = p[1];
    ushort8v v;
    v[0] = f2bf(a.x); v[1] = f2bf(a.y); v[2] = f2bf(a.z); v[3] = f2bf(a.w);
    v[4] = f2bf(b.x); v[5] = f2bf(b.y); v[6] = f2bf(b.z); v[7] = f2bf(b.w);
    *((ushort8v*)xb + i) = v;
    return;
  }
  int idx = i - n8;
  if (idx >= t8) return;
  int perRow = K >> 3;
  int n = idx / perRow;
  int d0 = (idx - n * perRow) << 3;
  const float4* wp = (const float4*)(W + (size_t)n * K + d0);
  float4 w0 = wp[0], w1 = wp[1];
  float acc[8] = {w0.x, w0.y, w0.z, w0.w, w1.x, w1.y, w1.z, w1.w};
#pragma unroll 4
  for (int r = 0; r < R; ++r) {
    float c = Bm[(size_t)n * R + r] * scale;
    const float4* ap = (const float4*)(A + (size_t)r * K + d0);
    float4 a0 = ap[0], a1 = ap[1];
    acc[0] += c * a0.x; acc[1] += c * a0.y; acc[2] += c * a0.z; acc[3] += c * a0.w;
    acc[4] += c * a1.x; acc[5] += c * a1.y; acc[6] += c * a1.z; acc[7] += c * a1.w;
  }
  ushort8v v;
#pragma unroll
  for (int j = 0; j < 8; ++j) v[j] = f2bf(acc[j]);
  *((ushort8v*)wb + idx) = v;
}

// ----- 128x128 bf16 GEMM: pipelined block x 2 blocks/CU (inter-block TLP) -----
// 4 waves (2Mx2N, wave 64x64, acc 64 VGPR), BK=64, 2 LDS buffers (2x32KB = 64KB)
// -> 2 blocks/CU (8 waves, 2/SIMD: one wave of EACH block per SIMD; block A's
// barrier/wait windows are covered by block B's MFMAs -- the m114 mechanism).
// Per K-step: 4 quarter-phases {reads | 2 stages | [vmcnt] | SBAR | lgkm(0) |
// 8 MFMA | SBAR}; B read once per step (P1), A quarter per phase.
// Stage ledger (tile c+1): P1 A-s0,A-s2; P2 B-s0,B-s1; P3 B-s2,B-s3; P4 A-s1,A-s3.
// Cert: vmcnt(4)@P2 certifies A-s1,s3(c) [staged P4(c-1), age 2]; vmcnt(2)@P4
// certifies B(c+1)+A-s0,s2(c+1) for next P1. Tail step: no stages, vmcnt 0/0.
// Buffer (bytes): A[128][64] @[0,16384); B[128][64] @[16384,32768); buf1 +32768.
// Swizzle: 16B-chunk q of row r holds global chunk q^(r&7) (measured 0 conflicts).
__global__ __launch_bounds__(256, 2) void gemm128mb_bt_bias(const unsigned short* __restrict__ Xb,
                                                            const unsigned short* __restrict__ Wb,
                                                            const float* __restrict__ bias,
                                                            float* __restrict__ C,
                                                            int M, int N, int K) {
  __shared__ __align__(16) char lds[65536];
  const int t = threadIdx.x;
  const int wave = t >> 6, lane = t & 63;
  const int fr = lane & 15, kc = lane >> 4;
  const int wr = wave >> 1, wc = wave & 1;

  const int NTn = N >> 7;
  const int nwg = gridDim.x;
  int bid = blockIdx.x;
  if ((nwg & 7) == 0) bid = (bid & 7) * (nwg >> 3) + (bid >> 3);  // XCD swizzle
  const int tm = bid / NTn, tn = bid % NTn;
  const int m0 = tm << 7, n0 = tn << 7;

  // staging sources (pre-swizzled global chunk); site = 32 rows = 4KB
  const int srow = t >> 3;
  const int gch8 = ((t & 7) ^ (srow & 7)) << 3;
  const unsigned short* pa0 = Xb + (size_t)(m0 + srow) * K + gch8;
  const unsigned short* pb0 = Wb + (size_t)(n0 + srow) * K + gch8;
  const size_t K32 = (size_t)32 * K;
  const int sdst = t * 16;

  // read base pointers (conflict-free swizzle, measured 0)
  const int swz = (fr & 7) << 4;
  const int cb0 = (kc << 4) ^ swz;
  const int cb1 = ((4 + kc) << 4) ^ swz;
  const char* rA0[2] = { (char*)lds + (wr * 64 + fr) * 128 + cb0,
                         (char*)lds + 32768 + (wr * 64 + fr) * 128 + cb0 };
  const char* rA1[2] = { (char*)lds + (wr * 64 + fr) * 128 + cb1,
                         (char*)lds + 32768 + (wr * 64 + fr) * 128 + cb1 };
  const char* rB0[2] = { (char*)lds + 16384 + (wc * 64 + fr) * 128 + cb0,
                         (char*)lds + 49152 + (wc * 64 + fr) * 128 + cb0 };
  const char* rB1[2] = { (char*)lds + 16384 + (wc * 64 + fr) * 128 + cb1,
                         (char*)lds + 49152 + (wc * 64 + fr) * 128 + cb1 };

  f32x4 acc[4][4];
#pragma unroll
  for (int m = 0; m < 4; ++m)
#pragma unroll
    for (int n = 0; n < 4; ++n) acc[m][n] = (f32x4){0.f, 0.f, 0.f, 0.f};

  bf16x8 aQ[2], bQ[8];

#define GL(PSRC, DOFF) gload_lds16((PSRC), (unsigned short*)((char*)lds + (DOFF) + sdst))
#define STG_A(BUF, s, COL) GL(pa0 + (size_t)(s) * K32 + (COL), (BUF) * 32768 + (s) * 4096)
#define STG_B(BUF, s, COL) GL(pb0 + (size_t)(s) * K32 + (COL), (BUF) * 32768 + 16384 + (s) * 4096)

#define RD_B(BUF) do { \
    bQ[0]=*(const bf16x8*)(rB0[BUF]);        bQ[1]=*(const bf16x8*)(rB1[BUF]); \
    bQ[2]=*(const bf16x8*)(rB0[BUF]+2048);   bQ[3]=*(const bf16x8*)(rB1[BUF]+2048); \
    bQ[4]=*(const bf16x8*)(rB0[BUF]+4096);   bQ[5]=*(const bf16x8*)(rB1[BUF]+4096); \
    bQ[6]=*(const bf16x8*)(rB0[BUF]+6144);   bQ[7]=*(const bf16x8*)(rB1[BUF]+6144); } while (0)
#define RD_A(BUF, mq) do { \
    aQ[0]=*(const bf16x8*)(rA0[BUF]+(mq)*2048); \
    aQ[1]=*(const bf16x8*)(rA1[BUF]+(mq)*2048); } while (0)

#define MMQ(mq) do { __builtin_amdgcn_s_setprio(1); \
    _Pragma("unroll") for (int nf = 0; nf < 4; ++nf) \
    _Pragma("unroll") for (int ks = 0; ks < 2; ++ks) \
      acc[mq][nf] = __builtin_amdgcn_mfma_f32_16x16x32_bf16( \
          aQ[ks], bQ[nf*2+ks], acc[mq][nf], 0, 0, 0); \
    __builtin_amdgcn_s_setprio(0); } while (0)

#define STEP(BUF, DOSTG, VM2, VM4) do { \
    /* P1: B full + A mq0; stage A-s0,A-s2(c+1) */ \
    RD_B(BUF); RD_A(BUF, 0); \
    if (DOSTG) { STG_A(BUF^1, 0, col); STG_A(BUF^1, 2, col); } \
    SBAR(); LGKM0(); MMQ(0); SBAR(); \
    /* P2: A mq1; stage B-s0,B-s1(c+1); certify A-s1,s3(c) */ \
    RD_A(BUF, 1); \
    if (DOSTG) { STG_B(BUF^1, 0, col); STG_B(BUF^1, 1, col); } \
    asm volatile("s_waitcnt vmcnt(" VM2 ")" ::: "memory"); \
    SBAR(); LGKM0(); MMQ(1); SBAR(); \
    /* P3: A mq2; stage B-s2,B-s3(c+1) */ \
    RD_A(BUF, 2); \
    if (DOSTG) { STG_B(BUF^1, 2, col); STG_B(BUF^1, 3, col); } \
    SBAR(); LGKM0(); MMQ(2); SBAR(); \
    /* P4: A mq3; stage A-s1,A-s3(c+1); certify B(c+1)+A-s0,s2(c+1) */ \
    RD_A(BUF, 3); \
    if (DOSTG) { STG_A(BUF^1, 1, col); STG_A(BUF^1, 3, col); } \
    asm volatile("s_waitcnt vmcnt(" VM4 ")" ::: "memory"); \
    SBAR(); LGKM0(); MMQ(3); SBAR(); \
    if (DOSTG) col += 64; \
  } while (0)

  // prologue: tile0 {A-s0,A-s2,B0..3} then {A-s1,A-s3}; vmcnt(2) certifies the
  // first 6 and leaves A-s1,s3(0) in flight = the steady-state "P4(-1)" pair.
  size_t col = 0;
  STG_A(0, 0, 0); STG_A(0, 2, 0);
  STG_B(0, 0, 0); STG_B(0, 1, 0); STG_B(0, 2, 0); STG_B(0, 3, 0);
  STG_A(0, 1, 0); STG_A(0, 3, 0);
  asm volatile("s_waitcnt vmcnt(2)" ::: "memory");
  SBAR();
  col = 64;

  const int NT = K >> 6;   // even (K % 128 == 0 enforced by launcher)
  for (int s2 = 0; s2 < NT - 2; s2 += 2) {
    STEP(0, 1, "4", "2");
    STEP(1, 1, "4", "2");
  }
  STEP(0, 1, "4", "2");   // step NT-2: stages tile NT-1
  STEP(1, 0, "0", "0");   // step NT-1: no staging, drain

  // epilogue: D map col = lane&15, row = (lane>>4)*4 + reg
  const int crow = (lane >> 4) * 4;
  const int ccol = lane & 15;
#pragma unroll
  for (int n = 0; n < 4; ++n) {
    int colI = n0 + wc * 64 + n * 16 + ccol;
    float bv = bias[colI];
#pragma unroll
    for (int m = 0; m < 4; ++m) {
      int row = m0 + wr * 64 + m * 16 + crow;
      float* cp = C + (size_t)row * N + colI;
#pragma unroll
      for (int r = 0; r < 4; ++r) cp[(size_t)r * N] = acc[m][n][r] + bv;
    }
  }
#undef GL
#undef STG_A
#undef STG_B
#undef RD_B
#undef RD_A
#undef MMQ
#undef STEP
}

// ---------------- 128x128 m97-structure fallback GEMM ----------------
__global__ __launch_bounds__(256) void gemm_bt_bias(const unsigned short* __restrict__ Xb,
                                                    const unsigned short* __restrict__ Wb,
                                                    const float* __restrict__ bias,
                                                    float* __restrict__ C,
                                                    int M, int N, int K) {
  __shared__ unsigned short sA[128 * 32];
  __shared__ unsigned short sB[128 * 32];
  const int t = threadIdx.x;
  const int wave = t >> 6, lane = t & 63;
  const int NT = N >> 7;
  const int nwg = gridDim.x;
  int bid = blockIdx.x;
  if ((nwg & 7) == 0) bid = (bid & 7) * (nwg >> 3) + (bid >> 3);
  const int tm = bid / NT, tn = bid % NT;
  const int m0 = tm << 7, n0 = tn << 7;
  const int wr = wave >> 1, wc = wave & 1;

  f32x4 acc[4][4];
#pragma unroll
  for (int m = 0; m < 4; ++m)
#pragma unroll
    for (int n = 0; n < 4; ++n) acc[m][n] = (f32x4){0.f, 0.f, 0.f, 0.f};

  const unsigned short* gA0 = Xb + (size_t)(m0 + (t >> 2)) * K + (t & 3) * 8;
  const unsigned short* gA1 = Xb + (size_t)(m0 + 64 + (t >> 2)) * K + (t & 3) * 8;
  const unsigned short* gB0 = Wb + (size_t)(n0 + (t >> 2)) * K + (t & 3) * 8;
  const unsigned short* gB1 = Wb + (size_t)(n0 + 64 + (t >> 2)) * K + (t & 3) * 8;
  unsigned short* lA0 = sA + (size_t)(wave * 64) * 8;
  unsigned short* lA1 = sA + (size_t)(256 + wave * 64) * 8;
  unsigned short* lB0 = sB + (size_t)(wave * 64) * 8;
  unsigned short* lB1 = sB + (size_t)(256 + wave * 64) * 8;

  const int rrow = lane & 15;
  const int rk = (lane >> 4) * 8;

  for (int k0 = 0; k0 < K; k0 += 32) {
    gload_lds16(gA0 + k0, lA0);
    gload_lds16(gA1 + k0, lA1);
    gload_lds16(gB0 + k0, lB0);
    gload_lds16(gB1 + k0, lB1);
    __syncthreads();
    bf16x8 af[4], bfr[4];
#pragma unroll
    for (int m = 0; m < 4; ++m)
      af[m] = *(const bf16x8*)&sA[(size_t)(wr * 64 + m * 16 + rrow) * 32 + rk];
#pragma unroll
    for (int n = 0; n < 4; ++n)
      bfr[n] = *(const bf16x8*)&sB[(size_t)(wc * 64 + n * 16 + rrow) * 32 + rk];
#pragma unroll
    for (int m = 0; m < 4; ++m)
#pragma unroll
      for (int n = 0; n < 4; ++n)
        acc[m][n] = __builtin_amdgcn_mfma_f32_16x16x32_bf16(af[m], bfr[n], acc[m][n], 0, 0, 0);
    __syncthreads();
  }
  const int crow0 = (lane >> 4) * 4;
  const int ccol = lane & 15;
#pragma unroll
  for (int n = 0; n < 4; ++n) {
    int col = n0 + wc * 64 + n * 16 + ccol;
    float bv = bias[col];
#pragma unroll
    for (int m = 0; m < 4; ++m) {
      int row = m0 + wr * 64 + m * 16 + crow0;
      float* cp = C + (size_t)row * N + col;
#pragma unroll
      for (int r = 0; r < 4; ++r) cp[(size_t)r * N] = acc[m][n][r] + bv;
    }
  }
}

// ---------------- fp32 fallback ----------------
__global__ __launch_bounds__(64) void lora_h_kernel(const float* __restrict__ x,
                                                    const float* __restrict__ A,
                                                    float* __restrict__ h,
                                                    float scale, int K, int R) {
  int m = blockIdx.x, lane = threadIdx.x;
  float acc[16];
#pragma unroll
  for (int r = 0; r < 16; ++r) acc[r] = 0.f;
  for (int d = lane; d < K; d += 64) {
    float xv = x[(size_t)m * K + d];
    for (int r = 0; r < R; ++r) acc[r] += xv * A[(size_t)r * K + d];
  }
  for (int off = 32; off; off >>= 1)
    for (int r = 0; r < R; ++r) acc[r] += __shfl_down(acc[r], off);
  if (lane == 0)
    for (int r = 0; r < R; ++r) h[(size_t)m * R + r] = acc[r] * scale;
}

__global__ __launch_bounds__(256) void fgemm_fallback(const float* __restrict__ X,
                                                      const float* __restrict__ W,
                                                      const float* __restrict__ Bm,
                                                      const float* __restrict__ bias,
                                                      const float* __restrict__ h,
                                                      float* __restrict__ C,
                                                      int M, int N, int K, int R) {
  __shared__ float sX[64][20];
  __shared__ float sW[64][20];
  int nt = N >> 6;
  int bx = blockIdx.x % nt, by = blockIdx.x / nt;
  int m0 = by << 6, n0 = bx << 6;
  int t = threadIdx.x;
  int tx = t & 15, ty = t >> 4;
  float acc[4][4] = {};
  int lrr = t >> 2, lc = (t & 3) << 2;
  for (int k0 = 0; k0 < K; k0 += 16) {
    *(float4*)&sX[lrr][lc] = *(const float4*)&X[(size_t)(m0 + lrr) * K + k0 + lc];
    *(float4*)&sW[lrr][lc] = *(const float4*)&W[(size_t)(n0 + lrr) * K + k0 + lc];
    __syncthreads();
#pragma unroll
    for (int kk = 0; kk < 16; ++kk) {
      float a[4], b[4];
#pragma unroll
      for (int i = 0; i < 4; ++i) a[i] = sX[ty * 4 + i][kk];
#pragma unroll
      for (int j = 0; j < 4; ++j) b[j] = sW[tx * 4 + j][kk];
#pragma unroll
      for (int i = 0; i < 4; ++i)
#pragma unroll
        for (int j = 0; j < 4; ++j) acc[i][j] += a[i] * b[j];
    }
    __syncthreads();
  }
#pragma unroll
  for (int i = 0; i < 4; ++i) {
    int row = m0 + ty * 4 + i;
#pragma unroll
    for (int j = 0; j < 4; ++j) {
      int col = n0 + tx * 4 + j;
      float lo = 0.f;
      for (int r = 0; r < R; ++r) lo += h[(size_t)row * R + r] * Bm[(size_t)col * R + r];
      C[(size_t)row * N + col] = acc[i][j] + bias[col] + lo;
    }
  }
}

extern "C" void kernel_launch(void* const* d_in, const int* in_sizes, int n_in,
                              void* d_out, int out_size, void* d_ws, size_t ws_size,
                              hipStream_t stream) {
  const float* x    = (const float*)d_in[0];
  const float* W    = (const float*)d_in[1];
  const float* A    = (const float*)d_in[2];
  const float* Bm   = (const float*)d_in[3];
  const float* bias = (const float*)d_in[4];
  float* out = (float*)d_out;

  const int N = in_sizes[4];
  const int R = in_sizes[3] / N;
  const int K = in_sizes[2] / R;
  const int M = in_sizes[0] / K;
  const float scale = 16.0f / (float)R;

  const size_t xbytes = (size_t)M * K * 2;
  const size_t wbytes = (size_t)N * K * 2;
  const bool ws_ok = (ws_size >= xbytes + wbytes);
  const bool fastMB  = ws_ok && (M % 128 == 0) && (N % 128 == 0) && (K % 128 == 0) && (K >= 256);
  const bool fast128 = ws_ok && (M % 128 == 0) && (N % 128 == 0) && (K % 32 == 0);

  if (fastMB || fast128) {
    unsigned short* xb = (unsigned short*)d_ws;
    unsigned short* wb = (unsigned short*)((char*)d_ws + xbytes);
    int n8 = M * K / 8;
    int t8 = N * K / 8;
    int total = n8 + t8;
    prep_kernel<<<dim3((total + 255) / 256), dim3(256), 0, stream>>>(x, W, A, Bm, xb, wb,
                                                                     scale, K, R, n8, t8);
    if (fastMB) {
      int grid = (M / 128) * (N / 128);
      gemm128mb_bt_bias<<<dim3(grid), dim3(256), 0, stream>>>(xb, wb, bias, out, M, N, K);
    } else {
      int grid = (M / 128) * (N / 128);
      gemm_bt_bias<<<dim3(grid), dim3(256), 0, stream>>>(xb, wb, bias, out, M, N, K);
    }
  } else {
    float* h = (float*)d_ws;
    lora_h_kernel<<<dim3(M), dim3(64), 0, stream>>>(x, A, h, scale, K, R);
    int grid = (M / 64) * (N / 64);
    fgemm_fallback<<<dim3(grid), dim3(256), 0, stream>>>(x, W, Bm, bias, h, out, M, N, K, R);
  }
}